// Round 5
// baseline (36.346 us; speedup 1.0000x reference)
//
#include <hip/hip_runtime.h>

#define HH 224
#define WW 224
#define K 15
#define PAD 7
#define BX 32
#define BY 8
#define TW (BX + K - 1)   /* 46 */
#define TH (BY + K - 1)   /* 22 */
#define TSTRIDE 48        /* row-to-row bank shift = 16 -> 2-way aliasing (free, m136) */

__global__ __launch_bounds__(BX * BY)
void bilateral_denoise_kernel(const float* __restrict__ x,
                              const float* __restrict__ blur_sigma_p,
                              const float* __restrict__ diff_sigma_p,
                              float* __restrict__ out)
{
    __shared__ float tile[TH * TSTRIDE];

    const int tx = threadIdx.x;           // 0..31
    const int ty = threadIdx.y;           // 0..7
    const int tid = ty * BX + tx;
    const int w0 = blockIdx.x * BX;
    const int h0 = blockIdx.y * BY;
    const int plane = blockIdx.z;         // b*C + c, 0..5

    const float* __restrict__ xp = x + (size_t)plane * HH * WW;

    // ---- stage halo tile (boundary -> -100, matching constant pad) ----
    for (int idx = tid; idx < TH * TW; idx += BX * BY) {
        const int r = idx / TW;
        const int c = idx - r * TW;
        const int gh = h0 - PAD + r;
        const int gw = w0 - PAD + c;
        float v = -100.0f;
        if (gh >= 0 && gh < HH && gw >= 0 && gw < WW) v = xp[gh * WW + gw];
        tile[r * TSTRIDE + c] = v;
    }
    __syncthreads();

    const float bs = blur_sigma_p[0];
    const float ds = diff_sigma_p[0];
    const float LOG2E = 1.44269504088896340736f;
    const float na  = -LOG2E / (ds * ds);   // scale on (v-cv)^2
    const float nk2 = -LOG2E / (bs * bs);   // scale on spatial squared distance

    const float cv = tile[(ty + PAD) * TSTRIDE + tx + PAD];
    // na*(v-cv)^2 = na*v^2 + bb*v + cc
    const float bb = -2.0f * na * cv;
    const float cc = na * cv * cv;

    float colw[K];
    float colv[K];
#pragma unroll
    for (int j = 0; j < K; ++j) { colw[j] = 0.0f; colv[j] = 0.0f; }

#pragma unroll
    for (int i = 0; i < K; ++i) {
        const float ci = __builtin_fmaf((float)((i - PAD) * (i - PAD)), nk2, cc);
        const float* __restrict__ row = &tile[(ty + i) * TSTRIDE + tx];
#pragma unroll
        for (int j = 0; j < K; ++j) {
            const float v = row[j];
            const float inner = __builtin_fmaf(v, na, bb);     // na*v + bb
            const float t = __builtin_fmaf(v, inner, ci);      // na*v^2 + bb*v + ci
            const float e = __builtin_amdgcn_exp2f(t);
            colw[j] += e;
            colv[j] = __builtin_fmaf(e, v, colv[j]);
        }
    }

    float wsum = 0.0f;
    float vsum = 0.0f;
#pragma unroll
    for (int j = 0; j < K; ++j) {
        const float wj = __builtin_amdgcn_exp2f((float)((j - PAD) * (j - PAD)) * nk2);
        wsum = __builtin_fmaf(wj, colw[j], wsum);
        vsum = __builtin_fmaf(wj, colv[j], vsum);
    }

    out[(size_t)plane * HH * WW + (size_t)(h0 + ty) * WW + (w0 + tx)] = vsum / wsum;
}

extern "C" void kernel_launch(void* const* d_in, const int* in_sizes, int n_in,
                              void* d_out, int out_size, void* d_ws, size_t ws_size,
                              hipStream_t stream) {
    const float* x  = (const float*)d_in[0];
    const float* bs = (const float*)d_in[1];
    const float* ds = (const float*)d_in[2];
    float* out = (float*)d_out;

    const int planes = in_sizes[0] / (HH * WW);   // B*C = 6
    dim3 grid(WW / BX, HH / BY, planes);          // 7 x 28 x 6 = 1176 blocks
    dim3 block(BX, BY, 1);

    // DIAGNOSTIC ROUND: launch the identical kernel TWICE (WAW -> serialized).
    // Measured dur = floor + 2*kernel. Compare vs single-launch 20.346 us:
    //   ~26-27 us -> kernel ~6 us, fixed floor ~14 us (floor hypothesis)
    //   ~40   us -> kernel ~20 us, kernel-bound (model must be rebuilt)
    hipLaunchKernelGGL(bilateral_denoise_kernel, grid, block, 0, stream,
                       x, bs, ds, out);
    hipLaunchKernelGGL(bilateral_denoise_kernel, grid, block, 0, stream,
                       x, bs, ds, out);
}

// Round 6
// 23.950 us; speedup vs baseline: 1.5176x; 1.5176x over previous
//
#include <hip/hip_runtime.h>

#define HH 224
#define WW 224
#define K 15
#define PAD 7
#define BX 32
#define BY 8
#define TW (BX + K - 1)   /* 46 used, stage full 48 */
#define TH (BY + K - 1)   /* 22 */
#define TSTRIDE 48        /* 192B rows: b128-aligned; bank shift 16/row -> 2-way (free) */
#define NSLOT 18          /* p + j, p in 0..3, j in 0..14 -> 0..17 */

__global__ __launch_bounds__(BX * BY)
void bilateral_denoise_kernel(const float* __restrict__ x,
                              const float* __restrict__ blur_sigma_p,
                              const float* __restrict__ diff_sigma_p,
                              float* __restrict__ out)
{
    __shared__ __align__(16) float tile[TH * TSTRIDE];

    const int tx = threadIdx.x;           // 0..31
    const int ty = threadIdx.y;           // 0..7
    const int w0 = blockIdx.x * BX;
    const int h0 = blockIdx.y * BY;
    const int plane = blockIdx.z;         // b*C + c, 0..5

    const float* __restrict__ xp = x + (size_t)plane * HH * WW;

    // ---- stage halo tile, FULL 48-wide (cols 46,47 -> -100, never garbage) ----
    for (int rr = ty; rr < TH; rr += BY) {
        const int gh = h0 - PAD + rr;
        for (int cc = tx; cc < TSTRIDE; cc += BX) {
            const int gw = w0 - PAD + cc;
            float v = -100.0f;
            if (gh >= 0 && gh < HH && gw >= 0 && gw < WW && cc < TW)
                v = xp[gh * WW + gw];
            tile[rr * TSTRIDE + cc] = v;
        }
    }
    __syncthreads();

    const float bs = blur_sigma_p[0];
    const float ds = diff_sigma_p[0];
    const float LOG2E = 1.44269504088896340736f;
    const float na  = -LOG2E / (ds * ds);   // scale on (v-cv)^2
    const float nk2 = -LOG2E / (bs * bs);   // scale on spatial squared distance

    const int ab = tx & ~3;                 // 16B-aligned read base (tile col)
    const int p  = tx & 3;                  // slot s holds window col j = s - p

    const float cv = tile[(ty + PAD) * TSTRIDE + tx + PAD];
    // na*(v-cv)^2 = na*v^2 + bb*v + cc2
    const float bb  = -2.0f * na * cv;
    const float cc2 = na * cv * cv;

    // per-slot column spatial weight (0 outside the window), computed once
    const float fp = (float)p;
    float wcol[NSLOT];
#pragma unroll
    for (int s = 0; s < NSLOT; ++s) {
        const float jj = (float)(s - PAD) - fp;          // j - 7
        const float wjs = __builtin_amdgcn_exp2f(jj * jj * nk2);
        const int j = s - p;
        wcol[s] = (j >= 0 && j < K) ? wjs : 0.0f;
    }

    float wsum = 0.0f;
    float vsum = 0.0f;

#pragma unroll
    for (int i = 0; i < K; ++i) {
        const float ci = __builtin_fmaf((float)((i - PAD) * (i - PAD)), nk2, cc2);
        const float4* __restrict__ rp =
            (const float4*)&tile[(ty + i) * TSTRIDE + ab];
        float r[20];
        *(float4*)&r[0]  = rp[0];   // 5x ds_read_b128 (vs 15x ds_read_b32)
        *(float4*)&r[4]  = rp[1];
        *(float4*)&r[8]  = rp[2];
        *(float4*)&r[12] = rp[3];
        *(float4*)&r[16] = rp[4];
#pragma unroll
        for (int s = 0; s < NSLOT; ++s) {
            const float v = r[s];
            const float inner = __builtin_fmaf(v, na, bb);   // na*v + bb
            const float t = __builtin_fmaf(v, inner, ci);    // na*v^2 + bb*v + ci
            const float e = __builtin_amdgcn_exp2f(t);       // range * row weight
            const float we = wcol[s] * e;                    // * column weight (0 if oob)
            wsum += we;
            vsum = __builtin_fmaf(we, v, vsum);
        }
    }

    out[(size_t)plane * HH * WW + (size_t)(h0 + ty) * WW + (w0 + tx)] = vsum / wsum;
}

extern "C" void kernel_launch(void* const* d_in, const int* in_sizes, int n_in,
                              void* d_out, int out_size, void* d_ws, size_t ws_size,
                              hipStream_t stream) {
    const float* x  = (const float*)d_in[0];
    const float* bs = (const float*)d_in[1];
    const float* ds = (const float*)d_in[2];
    float* out = (float*)d_out;

    const int planes = in_sizes[0] / (HH * WW);   // B*C = 6
    dim3 grid(WW / BX, HH / BY, planes);          // 7 x 28 x 6 = 1176 blocks
    dim3 block(BX, BY, 1);
    hipLaunchKernelGGL(bilateral_denoise_kernel, grid, block, 0, stream,
                       x, bs, ds, out);
}